// Round 6
// baseline (109.371 us; speedup 1.0000x reference)
//
#include <hip/hip_runtime.h>

// DmelsQuantizer: idx = argmin_k |x - codebook[k]|, first-min tie-breaking.
// For a sorted uniform codebook this equals the number of interval midpoints
// strictly below x (strict '>' reproduces argmin's pick-first-on-tie rule).
// OUTPUT IS int32 (harness reads d_out as np.int32) — store raw ints.
// Memory-bound: 123 MB total traffic -> ~20 us floor at 6.3 TB/s.

__global__ __launch_bounds__(256) void dmels_quant_kernel(
    const float* __restrict__ x,
    const float* __restrict__ cb,
    int* __restrict__ out,
    int n4, int n) {
  // Codebook is wave-uniform -> these become scalar loads, L1-cached.
  float mid[15];
#pragma unroll
  for (int k = 0; k < 15; ++k) mid[k] = 0.5f * (cb[k] + cb[k + 1]);

  const int tid = blockIdx.x * blockDim.x + threadIdx.x;
  const int stride = gridDim.x * blockDim.x;

  const float4* __restrict__ x4 = (const float4*)x;
  int4* __restrict__ o4 = (int4*)out;

  for (int i = tid; i < n4; i += stride) {
    float4 v = x4[i];
    int c0 = 0, c1 = 0, c2 = 0, c3 = 0;
#pragma unroll
    for (int k = 0; k < 15; ++k) {
      c0 += (v.x > mid[k]);
      c1 += (v.y > mid[k]);
      c2 += (v.z > mid[k]);
      c3 += (v.w > mid[k]);
    }
    o4[i] = make_int4(c0, c1, c2, c3);
  }

  // Scalar tail (n not divisible by 4) — n=15,360,000 is divisible, but be safe.
  for (int i = n4 * 4 + tid; i < n; i += stride) {
    float v = x[i];
    int c = 0;
#pragma unroll
    for (int k = 0; k < 15; ++k) c += (v > mid[k]);
    out[i] = c;
  }
}

extern "C" void kernel_launch(void* const* d_in, const int* in_sizes, int n_in,
                              void* d_out, int out_size, void* d_ws, size_t ws_size,
                              hipStream_t stream) {
  const float* x = (const float*)d_in[0];
  const float* cb = (const float*)d_in[1];
  int* out = (int*)d_out;

  const int n = in_sizes[0];
  const int n4 = n / 4;

  const int block = 256;
  int grid = (n4 + block - 1) / block;
  if (grid > 2560) grid = 2560;  // grid-stride; ~10 blocks/CU
  if (grid < 1) grid = 1;

  dmels_quant_kernel<<<grid, block, 0, stream>>>(x, cb, out, n4, n);
}